// Round 6
// baseline (172.292 us; speedup 1.0000x reference)
//
#include <hip/hip_runtime.h>
#include <cstdio>
#include <cmath>

#define TSEQ 2048
#define CDIM 1024
#define NBATCH 4

typedef float f32x4 __attribute__((ext_vector_type(4)));
typedef __bf16 bf16x8 __attribute__((ext_vector_type(8)));
typedef unsigned short u16;

// f32 -> bf16 round-to-nearest-even
__device__ __forceinline__ u16 f2bf(float f) {
  unsigned u = __builtin_bit_cast(unsigned, f);
  unsigned r = (u + 0x7FFFu + ((u >> 16) & 1u)) >> 16;
  return (u16)r;
}

// async global->LDS, 16B per lane; lds base wave-uniform (HW adds lane*16)
__device__ __forceinline__ void gload_lds16(const void* g, void* l) {
  __builtin_amdgcn_global_load_lds(
      (__attribute__((address_space(1))) void*)g,
      (__attribute__((address_space(3))) void*)l, 16, 0, 0);
}

// ---------------------------------------------------------------------------
// Shared 8-wave BM=256 x BN=128 x BK=64 core (m201-style 2-phase/K-tile
// interleave, counted vmcnt, T2 3-bit XOR swizzle, setprio).
// 512 thr = 8 waves: wrA = w>>1 (64-row group), wcB = w&1 (64-col group).
// Wave tile 64x64: acc[4][4] of 16x16x32 MFMA.
// LDS 96 KiB: Ab[2 buf][2 half][128*64] + Bb[2 buf][128*64] bf16.
// Stage stream per K-tile t: {B, A0, A1}; during tile T stage A1(T+1),
// B(T+2) [phase0] and A0(T+2) [phase1]; vmcnt(4) at tile end guarantees
// tile T+1 resident; vmcnt(0) at T = nT-2. nT must be EVEN, >= 2.
// ---------------------------------------------------------------------------
#define SWZ2(b_) ((b_) ^ ((((b_) >> 7) & 7) << 4))
#define AOFF(mf, ks) SWZ2(((arow + (mf) * 16 + frow) * 128 + (ks) * 64 + fko * 16))
#define BOFF(nf, ks) SWZ2(((wcB * 64 + (nf) * 16 + frow) * 128 + (ks) * 64 + fko * 16))

__device__ __forceinline__ void gemm256x128(
    const u16* __restrict__ A, const u16* __restrict__ B,
    int lda, int ldb, int m0, int n0, int nT,
    char* smem, f32x4 acc[4][4])
{
  u16* Ab = (u16*)smem;               // [2][2][8192] u16
  u16* Bb = (u16*)(smem + 65536);     // [2][8192] u16
  const int tid = threadIdx.x, w = tid >> 6, l = tid & 63;
  const int wrA = w >> 1, wcB = w & 1;
  const int ah = wrA >> 1;            // A half this wave reads
  const int arow = (wrA & 1) * 64;    // row base within the half
  const int frow = l & 15, fko = l >> 4;
  const int srow = l >> 3;
  const int scol = ((l & 7) * 8) ^ (((l >> 3) & 7) << 3);  // inverse-swz src col

  auto stage = [&](int t, int kind) {  // kind 0=B, 1=A0, 2=A1
    if (t >= nT) return;
    if (kind == 0) {
      const u16* gs = B + (size_t)(n0 + w * 16 + srow) * ldb + t * 64 + scol;
      u16* lb = Bb + (t & 1) * 8192 + w * 1024;
      gload_lds16(gs, lb);
      gload_lds16(gs + (size_t)8 * ldb, lb + 512);
    } else {
      const u16* gs = A + (size_t)(m0 + (kind - 1) * 128 + w * 16 + srow) * lda + t * 64 + scol;
      u16* lb = Ab + ((t & 1) * 2 + (kind - 1)) * 8192 + w * 1024;
      gload_lds16(gs, lb);
      gload_lds16(gs + (size_t)8 * lda, lb + 512);
    }
  };

#define KT(TT, PP, VMC) do {                                                  \
    const char* Abase = (const char*)Ab + ((PP) * 2 + ah) * 16384;            \
    const char* Bbase = (const char*)Bb + (PP) * 16384;                       \
    bf16x8 bfr[4][2];                                                         \
    _Pragma("unroll") for (int nf = 0; nf < 4; ++nf)                          \
    _Pragma("unroll") for (int ks = 0; ks < 2; ++ks)                          \
        bfr[nf][ks] = *(const bf16x8*)(Bbase + BOFF(nf, ks));                 \
    {  /* phase 0: mf 0,1 */                                                  \
      bf16x8 afr[2][2];                                                       \
      _Pragma("unroll") for (int mm = 0; mm < 2; ++mm)                        \
      _Pragma("unroll") for (int ks = 0; ks < 2; ++ks)                        \
          afr[mm][ks] = *(const bf16x8*)(Abase + AOFF(mm, ks));               \
      __builtin_amdgcn_sched_barrier(0);                                      \
      stage((TT) + 1, 2);                                                     \
      stage((TT) + 2, 0);                                                     \
      __builtin_amdgcn_s_barrier();                                           \
      __builtin_amdgcn_s_setprio(1);                                          \
      _Pragma("unroll") for (int ks = 0; ks < 2; ++ks)                        \
      _Pragma("unroll") for (int mm = 0; mm < 2; ++mm)                        \
      _Pragma("unroll") for (int nf = 0; nf < 4; ++nf)                        \
          acc[mm][nf] = __builtin_amdgcn_mfma_f32_16x16x32_bf16(              \
              afr[mm][ks], bfr[nf][ks], acc[mm][nf], 0, 0, 0);                \
      __builtin_amdgcn_s_setprio(0);                                          \
      __builtin_amdgcn_s_barrier();                                           \
    }                                                                         \
    {  /* phase 1: mf 2,3 */                                                  \
      bf16x8 afr[2][2];                                                       \
      _Pragma("unroll") for (int mm = 0; mm < 2; ++mm)                        \
      _Pragma("unroll") for (int ks = 0; ks < 2; ++ks)                        \
          afr[mm][ks] = *(const bf16x8*)(Abase + AOFF(2 + mm, ks));           \
      __builtin_amdgcn_sched_barrier(0);                                      \
      stage((TT) + 2, 1);                                                     \
      __builtin_amdgcn_s_barrier();                                           \
      __builtin_amdgcn_s_setprio(1);                                          \
      _Pragma("unroll") for (int ks = 0; ks < 2; ++ks)                        \
      _Pragma("unroll") for (int mm = 0; mm < 2; ++mm)                        \
      _Pragma("unroll") for (int nf = 0; nf < 4; ++nf)                        \
          acc[2 + mm][nf] = __builtin_amdgcn_mfma_f32_16x16x32_bf16(          \
              afr[mm][ks], bfr[nf][ks], acc[2 + mm][nf], 0, 0, 0);            \
      __builtin_amdgcn_s_setprio(0);                                          \
      if ((VMC) == 0) asm volatile("s_waitcnt vmcnt(4)" ::: "memory");        \
      else if ((VMC) == 1) asm volatile("s_waitcnt vmcnt(0)" ::: "memory");   \
      __builtin_amdgcn_s_barrier();                                           \
    }                                                                         \
  } while (0)

  // prologue: tile0 complete + B,A0 of tile1 in flight
  stage(0, 0); stage(0, 1); stage(0, 2); stage(1, 0); stage(1, 1);
  asm volatile("s_waitcnt vmcnt(4)" ::: "memory");
  __builtin_amdgcn_s_barrier();

#pragma unroll 1
  for (int T = 0; T < nT; T += 2) {
    const int last = (T == nT - 2);
    KT(T, 0, last ? 1 : 0);
    KT(T + 1, 1, last ? 2 : 0);
  }
#undef KT
}

// ---------------------------------------------------------------------------
// single cvt kernel for x, Wk, Wq, Wv
__global__ void __launch_bounds__(256) k_cvt_all(
    const float* __restrict__ x, const float* __restrict__ Wk,
    const float* __restrict__ Wq, const float* __restrict__ Wv,
    u16* __restrict__ xb, u16* __restrict__ wb)
{
  const int NX4 = (NBATCH * TSEQ * CDIM) / 4;
  const int NW4 = (CDIM * CDIM) / 4;
  int g = blockIdx.x * 256 + threadIdx.x;
  const float* src; u16* dst; int i;
  if (g < NX4) { src = x; dst = xb; i = g; }
  else {
    int g2 = g - NX4;
    int w = g2 / NW4; i = g2 - w * NW4;
    src = (w == 0) ? Wk : (w == 1) ? Wq : Wv;
    dst = wb + (size_t)w * CDIM * CDIM;
  }
  float4 v = ((const float4*)src)[i];
  ushort4 o;
  o.x = f2bf(v.x); o.y = f2bf(v.y); o.z = f2bf(v.z); o.w = f2bf(v.w);
  ((ushort4*)dst)[i] = o;
}

// ---------------------------------------------------------------------------
// QKV: A = xb [8192][1024], B = wb [3072][1024]. 768 blocks = 8 XCD x 96
// (4 m-panels pinned per XCD; nt slow so B-panel reused by 4 consecutive).
__global__ void __launch_bounds__(512) k_gemm_qkv_t(
    const u16* __restrict__ xb, const u16* __restrict__ wb,
    u16* __restrict__ kb, u16* __restrict__ qb, u16* __restrict__ vb)
{
  extern __shared__ char smem[];
  const int id = blockIdx.x;
  const int xcd = id & 7, loc = id >> 3;
  const int mt = xcd * 4 + (loc & 3);        // 0..31
  const int nt = loc >> 2;                   // 0..23
  const int m0 = mt * 256, n0g = nt * 128;

  f32x4 acc[4][4];
#pragma unroll
  for (int m_ = 0; m_ < 4; ++m_)
#pragma unroll
    for (int n_ = 0; n_ < 4; ++n_) acc[m_][n_] = (f32x4){0.f, 0.f, 0.f, 0.f};

  gemm256x128(xb, wb, CDIM, CDIM, m0, n0g, 16, smem, acc);

  const int tid = threadIdx.x, w = tid >> 6, l = tid & 63;
  const int wrA = w >> 1, wcB = w & 1;
  const int frow = l & 15, fko = l >> 4;
  const int z = n0g >> 10;
  u16* outp = (z == 0) ? kb : (z == 1) ? qb : vb;
  const float scale = (z == 1) ? 0.03125f : 1.0f;
  const int r0 = m0 + wrA * 64 + fko * 4;
  const int c0 = (n0g & 1023) + wcB * 64 + frow;
#pragma unroll
  for (int mf = 0; mf < 4; ++mf)
#pragma unroll
    for (int nf = 0; nf < 4; ++nf) {
      const int r = r0 + mf * 16;
      const int c = c0 + nf * 16;
#pragma unroll
      for (int j = 0; j < 4; ++j)
        outp[(size_t)(r + j) * CDIM + c] = f2bf(acc[mf][nf][j] * scale);
    }
}

// ---------------------------------------------------------------------------
// Scores: S = Q K^T -> P_unnorm = exp(S) bf16 + rowsum partials.
// 288 blocks = 8 XCD x 36; per-batch triangle y in 0..7 (256 q-rows),
// x in 0..2y+1 (128 k-cols).
__global__ void __launch_bounds__(512) k_gemm_scores_t(
    const u16* __restrict__ qb, const u16* __restrict__ kb,
    u16* __restrict__ pb, float* __restrict__ rs)
{
  extern __shared__ char smem[];
  const int id = blockIdx.x;
  const int sw = (id & 7) * 36 + (id >> 3);   // 0..287
  const int b = sw / 72;
  const int rem = sw - b * 72;                // 0..71
  int y = (int)((sqrtf(4.f * rem + 1.f) - 1.f) * 0.5f);
  while ((y + 1) * (y + 2) <= rem) ++y;
  while (y * (y + 1) > rem) --y;
  const int x = rem - y * (y + 1);            // 0..2y+1
  const int m0 = y * 256, n0 = x * 128;

  const u16* A = qb + (size_t)b * TSEQ * CDIM;
  const u16* B = kb + (size_t)b * TSEQ * CDIM;
  u16* P = pb + (size_t)b * TSEQ * TSEQ;

  f32x4 acc[4][4];
#pragma unroll
  for (int m_ = 0; m_ < 4; ++m_)
#pragma unroll
    for (int n_ = 0; n_ < 4; ++n_) acc[m_][n_] = (f32x4){0.f, 0.f, 0.f, 0.f};

  gemm256x128(A, B, CDIM, CDIM, m0, n0, 16, smem, acc);

  const int tid = threadIdx.x, w = tid >> 6, l = tid & 63;
  const int wrA = w >> 1, wcB = w & 1;
  const int frow = l & 15, fko = l >> 4;
  float* rowpart = (float*)smem;  // [256][2] overlay (GEMM LDS dead)

#pragma unroll
  for (int mf = 0; mf < 4; ++mf) {
#pragma unroll
    for (int j = 0; j < 4; ++j) {
      const int rloc = wrA * 64 + mf * 16 + fko * 4 + j;
      const int rglob = m0 + rloc;
      float p4 = 0.f;
#pragma unroll
      for (int nf = 0; nf < 4; ++nf) {
        const int c = n0 + wcB * 64 + nf * 16 + frow;
        float e = (c <= rglob) ? __expf(acc[mf][nf][j]) : 0.f;
        p4 += e;
        P[(size_t)rglob * TSEQ + c] = f2bf(e);
      }
#pragma unroll
      for (int d = 1; d < 16; d <<= 1) p4 += __shfl_xor(p4, d);
      if (frow == 0) rowpart[rloc * 2 + wcB] = p4;
    }
  }
  __syncthreads();
  if (tid < 256)
    rs[((size_t)b * 16 + (n0 >> 7)) * TSEQ + m0 + tid] =
        rowpart[tid * 2] + rowpart[tid * 2 + 1];
}

// ---------------------------------------------------------------------------
// legacy 128x128 core (pv)
__device__ __forceinline__ void gemm_core_128(
    const u16* __restrict__ A, const u16* __restrict__ B,
    int lda, int ldb, int m0, int n0, int kEnd,
    u16* As, u16* Bs, f32x4 acc[4][4])
{
  const int tid = threadIdx.x;
  const int w = tid >> 6, l = tid & 63;
  const int wr = w >> 1, wc = w & 1;
  const int srow = l >> 2;
  const int scol = (l & 3) * 8;
  const int fr = l & 15;
  const int fk = (l >> 4) * 8;

  for (int k0 = 0; k0 < kEnd; k0 += 32) {
    const u16* ga = A + (size_t)(m0 + w * 16 + srow) * lda + k0 + scol;
    gload_lds16(ga, As + w * 16 * 32);
    gload_lds16(ga + (size_t)64 * lda, As + (64 + w * 16) * 32);
    const u16* gb = B + (size_t)(n0 + w * 16 + srow) * ldb + k0 + scol;
    gload_lds16(gb, Bs + w * 16 * 32);
    gload_lds16(gb + (size_t)64 * ldb, Bs + (64 + w * 16) * 32);
    __syncthreads();

    bf16x8 af[4], bfv[4];
#pragma unroll
    for (int i = 0; i < 4; ++i)
      af[i] = *reinterpret_cast<const bf16x8*>(As + (wr * 64 + i * 16 + fr) * 32 + fk);
#pragma unroll
    for (int i = 0; i < 4; ++i)
      bfv[i] = *reinterpret_cast<const bf16x8*>(Bs + (wc * 64 + i * 16 + fr) * 32 + fk);
#pragma unroll
    for (int m = 0; m < 4; ++m)
#pragma unroll
      for (int n = 0; n < 4; ++n)
        acc[m][n] = __builtin_amdgcn_mfma_f32_16x16x32_bf16(af[m], bfv[n], acc[m][n], 0, 0, 0);
    __syncthreads();
  }
}

// V[2048][1024] -> Vt[1024][2048] per batch
__global__ void __launch_bounds__(256) k_transpose_v(const u16* __restrict__ vb,
                                                     u16* __restrict__ vt) {
  __shared__ u16 tile[32][33];
  const int b = blockIdx.z;
  const u16* V = vb + (size_t)b * TSEQ * CDIM;
  u16* Vt = vt + (size_t)b * CDIM * TSEQ;
  const int c0 = blockIdx.x * 32, r0 = blockIdx.y * 32;
  const int tx = threadIdx.x, ty = threadIdx.y;
#pragma unroll
  for (int j = 0; j < 4; ++j)
    tile[ty + j * 8][tx] = V[(size_t)(r0 + ty + j * 8) * CDIM + c0 + tx];
  __syncthreads();
#pragma unroll
  for (int j = 0; j < 4; ++j)
    Vt[(size_t)(c0 + ty + j * 8) * TSEQ + r0 + tx] = tile[tx][ty + j * 8];
}

// inv_rowsum[b][t] = 1 / sum_{x<=ytile} rs[b][x][t]
__global__ void __launch_bounds__(256) k_suminv(const float* __restrict__ rs,
                                                float* __restrict__ inv) {
  const int i = blockIdx.x * 256 + threadIdx.x;
  const int b = i >> 11, t = i & (TSEQ - 1), y = t >> 7;
  const float* p = rs + (size_t)b * 16 * TSEQ + t;
  float s = 0.f;
  for (int x = 0; x <= y; ++x) s += p[(size_t)x * TSEQ];
  inv[i] = 1.f / s;
}

// O = (P_unnorm @ V) * inv_rowsum; causal K-extent. XCD-chunked flat grid:
// 512 = 8 XCD x 64; within chunk n fastest -> P m-panel + Vt reuse in L2.
__global__ void __launch_bounds__(256) k_gemm_pv(
    const u16* __restrict__ pb, const u16* __restrict__ vt,
    const float* __restrict__ inv, float* __restrict__ out)
{
  __shared__ u16 As[128 * 32], Bs[128 * 32];
  const int id = blockIdx.x;
  const int sw = (id & 7) * 64 + (id >> 3);   // 0..511
  const int b = sw >> 7;
  const int rem = sw & 127;
  const int mt = rem >> 3, n = rem & 7;
  const int m0 = mt * 128, n0 = n * 128;
  const int kExt = (mt + 1) * 128;

  const u16* A = pb + (size_t)b * TSEQ * TSEQ;
  const u16* B = vt + (size_t)b * CDIM * TSEQ;
  float* O = out + (size_t)b * TSEQ * CDIM;
  f32x4 acc[4][4];
#pragma unroll
  for (int m_ = 0; m_ < 4; ++m_)
#pragma unroll
    for (int n_ = 0; n_ < 4; ++n_) acc[m_][n_] = (f32x4){0.f, 0.f, 0.f, 0.f};
  gemm_core_128(A, B, TSEQ, TSEQ, m0, n0, kExt, As, Bs, acc);

  const int tid = threadIdx.x, w = tid >> 6, l = tid & 63;
  const int wr = w >> 1, wc = w & 1;
#pragma unroll
  for (int m = 0; m < 4; ++m) {
    const int r = m0 + wr * 64 + m * 16 + ((l >> 4) << 2);
    const float4 iv = *(const float4*)&inv[(size_t)b * TSEQ + r];
    const float ivj[4] = {iv.x, iv.y, iv.z, iv.w};
#pragma unroll
    for (int nn = 0; nn < 4; ++nn) {
      const int c = n0 + wc * 64 + nn * 16 + (l & 15);
#pragma unroll
      for (int j = 0; j < 4; ++j)
        O[(size_t)(r + j) * CDIM + c] = acc[m][nn][j] * ivj[j];
    }
  }
}

// ---------------------------------------------------------------------------
extern "C" void kernel_launch(void* const* d_in, const int* in_sizes, int n_in,
                              void* d_out, int out_size, void* d_ws, size_t ws_size,
                              hipStream_t stream) {
  const float* x  = (const float*)d_in[0];
  const float* Wk = (const float*)d_in[1];
  const float* Wq = (const float*)d_in[2];
  const float* Wv = (const float*)d_in[3];
  float* out = (float*)d_out;

  const size_t M = (size_t)NBATCH * TSEQ;

  size_t off = 0;
  auto alloc = [&](size_t bytes) {
    void* p = (char*)d_ws + off;
    off += (bytes + 255) & ~(size_t)255;
    return p;
  };
  u16* xb = (u16*)alloc(M * CDIM * 2);
  u16* wb = (u16*)alloc(3ull * CDIM * CDIM * 2);
  u16* qb = (u16*)alloc(M * CDIM * 2);
  u16* kb = (u16*)alloc(M * CDIM * 2);
  u16* vb = (u16*)alloc(M * CDIM * 2);
  u16* pbuf = (u16*)alloc((size_t)NBATCH * TSEQ * TSEQ * 2);
  float* rs  = (float*)alloc((size_t)NBATCH * 16 * TSEQ * 4);
  float* inv = (float*)alloc(M * 4);
  if (off > ws_size) {
    fprintf(stderr, "kernel_launch: ws too small: need %zu, have %zu\n", off, ws_size);
    return;
  }
  u16* vt = xb;  // Vt overlay (x dead after QKV)

  const int NX4 = (NBATCH * TSEQ * CDIM) / 4;
  const int NW4 = (CDIM * CDIM) / 4;
  const int cvtBlocks = (NX4 + 3 * NW4) / 256;

  static_cast<void>(hipFuncSetAttribute(
      reinterpret_cast<const void*>(k_gemm_qkv_t),
      hipFuncAttributeMaxDynamicSharedMemorySize, 98304));
  static_cast<void>(hipFuncSetAttribute(
      reinterpret_cast<const void*>(k_gemm_scores_t),
      hipFuncAttributeMaxDynamicSharedMemorySize, 98304));

  k_cvt_all<<<cvtBlocks, 256, 0, stream>>>(x, Wk, Wq, Wv, xb, wb);
  k_gemm_qkv_t<<<768, 512, 98304, stream>>>(xb, wb, kb, qb, vb);
  k_transpose_v<<<dim3(CDIM / 32, TSEQ / 32, NBATCH), dim3(32, 8), 0, stream>>>(vb, vt);
  k_gemm_scores_t<<<288, 512, 98304, stream>>>(qb, kb, pbuf, rs);
  k_suminv<<<(int)(M / 256), 256, 0, stream>>>(rs, inv);
  k_gemm_pv<<<512, 256, 0, stream>>>(pbuf, vt, inv, out);
}

// Round 7
// 150.772 us; speedup vs baseline: 1.1427x; 1.1427x over previous
//
#include <hip/hip_runtime.h>
#include <cstdio>
#include <cmath>

#define TSEQ 2048
#define CDIM 1024
#define NBATCH 4

typedef float f32x4 __attribute__((ext_vector_type(4)));
typedef __bf16 bf16x8 __attribute__((ext_vector_type(8)));
typedef unsigned short u16;

// f32 -> bf16 round-to-nearest-even
__device__ __forceinline__ u16 f2bf(float f) {
  unsigned u = __builtin_bit_cast(unsigned, f);
  unsigned r = (u + 0x7FFFu + ((u >> 16) & 1u)) >> 16;
  return (u16)r;
}

// async global->LDS, 16B per lane; lds base wave-uniform (HW adds lane*16)
__device__ __forceinline__ void gload_lds16(const void* g, void* l) {
  __builtin_amdgcn_global_load_lds(
      (__attribute__((address_space(1))) void*)g,
      (__attribute__((address_space(3))) void*)l, 16, 0, 0);
}

// ---------------------------------------------------------------------------
// Uniform 4-wave 128x128 BK=64 GEMM core, 64 KiB LDS -> 2 blocks/CU (TLP
// covers barrier/vmcnt stalls). D[m,n] = sum_k A[m,k]*B[n,k], K-major bf16.
// 256 thr = 4 waves (2M x 2N), wave tile 64x64 = acc[4][4] of 16x16x32 MFMA.
// LDS: Ab[2][128][64] + Bb[2][128][64] u16 (128B rows), T2 3-bit XOR swizzle
// (write side: linear dest + inverse-permuted source col; read side: SWZ).
// Stream: ph0 of tile t stages B(t+2), ph1 stages A(t+2) (writes race-safe:
// reads of tile t issue pre-barrier, writes arrive >=200cy later — m201
// precedent). vmcnt(8) at tile end (2 stages in flight), vmcnt(0) at nT-2.
// nT must be EVEN >= 2.
// ---------------------------------------------------------------------------
#define SWZ2(b_) ((b_) ^ ((((b_) >> 7) & 7) << 4))

__device__ __forceinline__ void gemm128(
    const u16* __restrict__ A, const u16* __restrict__ B,
    int lda, int ldb, int m0, int n0, int nT,
    char* smem, f32x4 acc[4][4])
{
  u16* Ab = (u16*)smem;               // [2][128*64]
  u16* Bb = (u16*)(smem + 32768);     // [2][128*64]
  const int tid = threadIdx.x, w = tid >> 6, l = tid & 63;
  const int wr = w >> 1, wc = w & 1;
  const int frow = l & 15, fko = l >> 4;
  const int srow = l >> 3;            // 8 rows per gload
  const int scol = ((l & 7) * 8) ^ (((l >> 3) & 7) << 3);  // inverse-swz src col

  const u16* gA = A + (size_t)(m0 + w * 32 + srow) * lda + scol;
  const u16* gB = B + (size_t)(n0 + w * 32 + srow) * ldb + scol;

  auto stageA = [&](int t) {          // 128x64 tile: 4 gloads/thread
    if (t >= nT) return;
    const u16* s = gA + t * 64;
    u16* d = Ab + (t & 1) * 8192 + w * 2048;
    gload_lds16(s, d);
    gload_lds16(s + (size_t)8 * lda, d + 512);
    gload_lds16(s + (size_t)16 * lda, d + 1024);
    gload_lds16(s + (size_t)24 * lda, d + 1536);
  };
  auto stageB = [&](int t) {
    if (t >= nT) return;
    const u16* s = gB + t * 64;
    u16* d = Bb + (t & 1) * 8192 + w * 2048;
    gload_lds16(s, d);
    gload_lds16(s + (size_t)8 * ldb, d + 512);
    gload_lds16(s + (size_t)16 * ldb, d + 1024);
    gload_lds16(s + (size_t)24 * ldb, d + 1536);
  };

#define AOFF(mf, ks) SWZ2(((wr * 64 + (mf) * 16 + frow) * 128 + (ks) * 64 + fko * 16))
#define BOFF(nf, ks) SWZ2(((wc * 64 + (nf) * 16 + frow) * 128 + (ks) * 64 + fko * 16))

  // prologue: tiles 0,1 fully staged; wait tile0 (8 newest may remain)
  stageB(0); stageA(0); stageB(1); stageA(1);
  asm volatile("s_waitcnt vmcnt(8)" ::: "memory");
  __builtin_amdgcn_s_barrier();

#pragma unroll 1
  for (int t = 0; t < nT; ++t) {
    const char* Abase = (const char*)Ab + (t & 1) * 16384;
    const char* Bbase = (const char*)Bb + (t & 1) * 16384;
    // ---- phase 0: all B-frags + A-frags mf 0,1
    bf16x8 bfr[4][2], af0[2][2];
#pragma unroll
    for (int nf = 0; nf < 4; ++nf)
#pragma unroll
      for (int ks = 0; ks < 2; ++ks)
        bfr[nf][ks] = *(const bf16x8*)(Bbase + BOFF(nf, ks));
#pragma unroll
    for (int mm = 0; mm < 2; ++mm)
#pragma unroll
      for (int ks = 0; ks < 2; ++ks)
        af0[mm][ks] = *(const bf16x8*)(Abase + AOFF(mm, ks));
    __builtin_amdgcn_sched_barrier(0);
    stageB(t + 2);
    __builtin_amdgcn_s_barrier();
    __builtin_amdgcn_s_setprio(1);
#pragma unroll
    for (int ks = 0; ks < 2; ++ks)
#pragma unroll
      for (int mm = 0; mm < 2; ++mm)
#pragma unroll
        for (int nf = 0; nf < 4; ++nf)
          acc[mm][nf] = __builtin_amdgcn_mfma_f32_16x16x32_bf16(
              af0[mm][ks], bfr[nf][ks], acc[mm][nf], 0, 0, 0);
    __builtin_amdgcn_s_setprio(0);
    __builtin_amdgcn_s_barrier();
    // ---- phase 1: A-frags mf 2,3
    bf16x8 af1[2][2];
#pragma unroll
    for (int mm = 0; mm < 2; ++mm)
#pragma unroll
      for (int ks = 0; ks < 2; ++ks)
        af1[mm][ks] = *(const bf16x8*)(Abase + AOFF(2 + mm, ks));
    __builtin_amdgcn_sched_barrier(0);
    stageA(t + 2);
    __builtin_amdgcn_s_barrier();
    __builtin_amdgcn_s_setprio(1);
#pragma unroll
    for (int ks = 0; ks < 2; ++ks)
#pragma unroll
      for (int mm = 0; mm < 2; ++mm)
#pragma unroll
        for (int nf = 0; nf < 4; ++nf)
          acc[2 + mm][nf] = __builtin_amdgcn_mfma_f32_16x16x32_bf16(
              af1[mm][ks], bfr[nf][ks], acc[2 + mm][nf], 0, 0, 0);
    __builtin_amdgcn_s_setprio(0);
    if (t < nT - 2) asm volatile("s_waitcnt vmcnt(8)" ::: "memory");
    else if (t == nT - 2) asm volatile("s_waitcnt vmcnt(0)" ::: "memory");
    __builtin_amdgcn_s_barrier();
  }
#undef AOFF
#undef BOFF
}

#define ACC_ZERO4(acc)                                  \
  _Pragma("unroll") for (int m_ = 0; m_ < 4; ++m_)      \
  _Pragma("unroll") for (int n_ = 0; n_ < 4; ++n_)      \
      acc[m_][n_] = (f32x4){0.f, 0.f, 0.f, 0.f};

// ---------------------------------------------------------------------------
// single cvt kernel for x, Wk, Wq, Wv
__global__ void __launch_bounds__(256) k_cvt_all(
    const float* __restrict__ x, const float* __restrict__ Wk,
    const float* __restrict__ Wq, const float* __restrict__ Wv,
    u16* __restrict__ xb, u16* __restrict__ wb)
{
  const int NX4 = (NBATCH * TSEQ * CDIM) / 4;
  const int NW4 = (CDIM * CDIM) / 4;
  int g = blockIdx.x * 256 + threadIdx.x;
  const float* src; u16* dst; int i;
  if (g < NX4) { src = x; dst = xb; i = g; }
  else {
    int g2 = g - NX4;
    int w = g2 / NW4; i = g2 - w * NW4;
    src = (w == 0) ? Wk : (w == 1) ? Wq : Wv;
    dst = wb + (size_t)w * CDIM * CDIM;
  }
  float4 v = ((const float4*)src)[i];
  ushort4 o;
  o.x = f2bf(v.x); o.y = f2bf(v.y); o.z = f2bf(v.z); o.w = f2bf(v.w);
  ((ushort4*)dst)[i] = o;
}

// ---------------------------------------------------------------------------
// QKV: A = xb [8192][1024], B = wb [3072][1024]. 1536 blocks = 8 XCD x 192.
// Per XCD: 8 m-panels (2MB x-rows L2-resident); nt slow (W panel shared).
__global__ void __launch_bounds__(256, 2) k_gemm_qkv_t(
    const u16* __restrict__ xb, const u16* __restrict__ wb,
    u16* __restrict__ kb, u16* __restrict__ qb, u16* __restrict__ vb)
{
  extern __shared__ char smem[];
  const int id = blockIdx.x;
  const int xcd = id & 7, loc = id >> 3;
  const int mt = xcd * 8 + (loc & 7);        // 0..63
  const int nt = loc >> 3;                   // 0..23
  const int m0 = mt * 128, n0g = nt * 128;

  f32x4 acc[4][4];
  ACC_ZERO4(acc);
  gemm128(xb, wb, CDIM, CDIM, m0, n0g, 16, smem, acc);

  const int tid = threadIdx.x, w = tid >> 6, l = tid & 63;
  const int wr = w >> 1, wc = w & 1;
  const int frow = l & 15, fko = l >> 4;
  const int z = n0g >> 10;
  u16* outp = (z == 0) ? kb : (z == 1) ? qb : vb;
  const float scale = (z == 1) ? 0.03125f : 1.0f;
  const int r0 = m0 + wr * 64 + fko * 4;
  const int c0 = (n0g & 1023) + wc * 64 + frow;
#pragma unroll
  for (int mf = 0; mf < 4; ++mf)
#pragma unroll
    for (int nf = 0; nf < 4; ++nf) {
      const int r = r0 + mf * 16;
      const int c = c0 + nf * 16;
#pragma unroll
      for (int j = 0; j < 4; ++j)
        outp[(size_t)(r + j) * CDIM + c] = f2bf(acc[mf][nf][j] * scale);
    }
}

// ---------------------------------------------------------------------------
// Scores: S = Q K^T -> P_unnorm = exp(S) bf16 (max-free) + rowsum partials.
// 544 blocks = 8 XCD x 68; per-batch 16x16 lower triangle of 128 tiles.
__global__ void __launch_bounds__(256, 2) k_gemm_scores_t(
    const u16* __restrict__ qb, const u16* __restrict__ kb,
    u16* __restrict__ pb, float* __restrict__ rs)
{
  extern __shared__ char smem[];
  const int id = blockIdx.x;
  const int sw = (id & 7) * 68 + (id >> 3);
  const int b = sw / 136;
  const int wq = sw - b * 136;
  int y = (int)((sqrtf(8.f * wq + 1.f) - 1.f) * 0.5f);
  while ((y + 1) * (y + 2) / 2 <= wq) ++y;
  while (y * (y + 1) / 2 > wq) --y;
  const int xt = wq - y * (y + 1) / 2;
  const int m0 = y * 128, n0 = xt * 128;

  const u16* A = qb + (size_t)b * TSEQ * CDIM;
  const u16* B = kb + (size_t)b * TSEQ * CDIM;
  u16* P = pb + (size_t)b * TSEQ * TSEQ;

  f32x4 acc[4][4];
  ACC_ZERO4(acc);
  gemm128(A, B, CDIM, CDIM, m0, n0, 16, smem, acc);

  const int tid = threadIdx.x, w = tid >> 6, l = tid & 63;
  const int wr = w >> 1, wc = w & 1;
  const int frow = l & 15, fko = l >> 4;
  float* rowpart = (float*)smem;  // [128][2] overlay (GEMM LDS dead)

#pragma unroll
  for (int mf = 0; mf < 4; ++mf) {
#pragma unroll
    for (int j = 0; j < 4; ++j) {
      const int rloc = wr * 64 + mf * 16 + fko * 4 + j;
      const int rglob = m0 + rloc;
      float p4 = 0.f;
#pragma unroll
      for (int nf = 0; nf < 4; ++nf) {
        const int c = n0 + wc * 64 + nf * 16 + frow;
        float e = (c <= rglob) ? __expf(acc[mf][nf][j]) : 0.f;
        p4 += e;
        P[(size_t)rglob * TSEQ + c] = f2bf(e);
      }
#pragma unroll
      for (int d = 1; d < 16; d <<= 1) p4 += __shfl_xor(p4, d);
      if (frow == 0) rowpart[rloc * 2 + wc] = p4;
    }
  }
  __syncthreads();
  if (tid < 128)
    rs[((size_t)b * 16 + xt) * TSEQ + m0 + tid] =
        rowpart[tid * 2] + rowpart[tid * 2 + 1];
}

// ---------------------------------------------------------------------------
// V[2048][1024] -> Vt[1024][2048] per batch
__global__ void __launch_bounds__(256) k_transpose_v(const u16* __restrict__ vb,
                                                     u16* __restrict__ vt) {
  __shared__ u16 tile[32][33];
  const int b = blockIdx.z;
  const u16* V = vb + (size_t)b * TSEQ * CDIM;
  u16* Vt = vt + (size_t)b * CDIM * TSEQ;
  const int c0 = blockIdx.x * 32, r0 = blockIdx.y * 32;
  const int tx = threadIdx.x, ty = threadIdx.y;
#pragma unroll
  for (int j = 0; j < 4; ++j)
    tile[ty + j * 8][tx] = V[(size_t)(r0 + ty + j * 8) * CDIM + c0 + tx];
  __syncthreads();
#pragma unroll
  for (int j = 0; j < 4; ++j)
    Vt[(size_t)(c0 + ty + j * 8) * TSEQ + r0 + tx] = tile[tx][ty + j * 8];
}

// inv_rowsum[b][t] = 1 / sum_{x<=ytile} rs[b][x][t]
__global__ void __launch_bounds__(256) k_suminv(const float* __restrict__ rs,
                                                float* __restrict__ inv) {
  const int i = blockIdx.x * 256 + threadIdx.x;
  const int b = i >> 11, t = i & (TSEQ - 1), y = t >> 7;
  const float* p = rs + (size_t)b * 16 * TSEQ + t;
  float s = 0.f;
  for (int x = 0; x <= y; ++x) s += p[(size_t)x * TSEQ];
  inv[i] = 1.f / s;
}

// ---------------------------------------------------------------------------
// O = (P_unnorm @ V) * inv_rowsum; causal K-extent nT = 2*(mt+1).
// 512 blocks = 8 XCD x 64; xcd = n (Vt panel resident), loc = b*16 + mt
// (every XCD gets the full mt spread -> balanced causal work).
__global__ void __launch_bounds__(256, 2) k_gemm_pv_t(
    const u16* __restrict__ pb, const u16* __restrict__ vt,
    const float* __restrict__ inv, float* __restrict__ out)
{
  extern __shared__ char smem[];
  const int id = blockIdx.x;
  const int n = id & 7, loc = id >> 3;
  const int b = loc >> 4, mt = loc & 15;
  const int m0 = mt * 128, n0 = n * 128;
  const int nT = 2 * (mt + 1);

  const u16* A = pb + (size_t)b * TSEQ * TSEQ;
  const u16* B = vt + (size_t)b * CDIM * TSEQ;
  float* O = out + (size_t)b * TSEQ * CDIM;

  f32x4 acc[4][4];
  ACC_ZERO4(acc);
  gemm128(A, B, TSEQ, TSEQ, m0, n0, nT, smem, acc);

  const int tid = threadIdx.x, w = tid >> 6, l = tid & 63;
  const int wr = w >> 1, wc = w & 1;
  const int frow = l & 15, fko = l >> 4;
#pragma unroll
  for (int mf = 0; mf < 4; ++mf) {
    const int r = m0 + wr * 64 + mf * 16 + fko * 4;
    const float4 iv = *(const float4*)&inv[(size_t)b * TSEQ + r];
    const float ivj[4] = {iv.x, iv.y, iv.z, iv.w};
#pragma unroll
    for (int nf = 0; nf < 4; ++nf) {
      const int c = n0 + wc * 64 + nf * 16 + frow;
#pragma unroll
      for (int j = 0; j < 4; ++j)
        O[(size_t)(r + j) * CDIM + c] = acc[mf][nf][j] * ivj[j];
    }
  }
}

// ---------------------------------------------------------------------------
extern "C" void kernel_launch(void* const* d_in, const int* in_sizes, int n_in,
                              void* d_out, int out_size, void* d_ws, size_t ws_size,
                              hipStream_t stream) {
  const float* x  = (const float*)d_in[0];
  const float* Wk = (const float*)d_in[1];
  const float* Wq = (const float*)d_in[2];
  const float* Wv = (const float*)d_in[3];
  float* out = (float*)d_out;

  const size_t M = (size_t)NBATCH * TSEQ;

  size_t off = 0;
  auto alloc = [&](size_t bytes) {
    void* p = (char*)d_ws + off;
    off += (bytes + 255) & ~(size_t)255;
    return p;
  };
  u16* xb = (u16*)alloc(M * CDIM * 2);
  u16* wb = (u16*)alloc(3ull * CDIM * CDIM * 2);
  u16* qb = (u16*)alloc(M * CDIM * 2);
  u16* kb = (u16*)alloc(M * CDIM * 2);
  u16* vb = (u16*)alloc(M * CDIM * 2);
  u16* pbuf = (u16*)alloc((size_t)NBATCH * TSEQ * TSEQ * 2);
  float* rs  = (float*)alloc((size_t)NBATCH * 16 * TSEQ * 4);
  float* inv = (float*)alloc(M * 4);
  if (off > ws_size) {
    fprintf(stderr, "kernel_launch: ws too small: need %zu, have %zu\n", off, ws_size);
    return;
  }
  u16* vt = xb;  // Vt overlay (x dead after QKV)

  const int NX4 = (NBATCH * TSEQ * CDIM) / 4;
  const int NW4 = (CDIM * CDIM) / 4;
  const int cvtBlocks = (NX4 + 3 * NW4) / 256;

  static_cast<void>(hipFuncSetAttribute(
      reinterpret_cast<const void*>(k_gemm_qkv_t),
      hipFuncAttributeMaxDynamicSharedMemorySize, 65536));
  static_cast<void>(hipFuncSetAttribute(
      reinterpret_cast<const void*>(k_gemm_scores_t),
      hipFuncAttributeMaxDynamicSharedMemorySize, 65536));
  static_cast<void>(hipFuncSetAttribute(
      reinterpret_cast<const void*>(k_gemm_pv_t),
      hipFuncAttributeMaxDynamicSharedMemorySize, 65536));

  k_cvt_all<<<cvtBlocks, 256, 0, stream>>>(x, Wk, Wq, Wv, xb, wb);
  k_gemm_qkv_t<<<1536, 256, 65536, stream>>>(xb, wb, kb, qb, vb);
  k_transpose_v<<<dim3(CDIM / 32, TSEQ / 32, NBATCH), dim3(32, 8), 0, stream>>>(vb, vt);
  k_gemm_scores_t<<<544, 256, 65536, stream>>>(qb, kb, pbuf, rs);
  k_suminv<<<(int)(M / 256), 256, 0, stream>>>(rs, inv);
  k_gemm_pv_t<<<512, 256, 65536, stream>>>(pbuf, vt, inv, out);
}